// Round 10
// baseline (316.391 us; speedup 1.0000x reference)
//
#include <hip/hip_runtime.h>

#define K_DIM 8192
#define M_OUT 1024
#define N_OUT 4096
#define BUFSZ 65536   // per-dbuf LDS: A 32 KiB + B 32 KiB

typedef __attribute__((ext_vector_type(4))) float f32x4;
typedef __attribute__((ext_vector_type(8))) __bf16 bf16x8;
typedef __attribute__((ext_vector_type(2))) __bf16 bf16x2;
typedef __attribute__((ext_vector_type(4))) unsigned u32x4;
typedef __attribute__((ext_vector_type(8))) unsigned short u16x8;

__device__ __forceinline__ unsigned short f2bf(float x) {
  unsigned u = __builtin_bit_cast(unsigned, x);
  u += 0x7fffu + ((u >> 16) & 1u);   // round-to-nearest-even
  return (unsigned short)(u >> 16);
}

__device__ __forceinline__ unsigned pack2(float a, float b) {
  bf16x2 v;
  v[0] = (__bf16)a;   // RNE; pairs lower to v_cvt_pk_bf16_f32
  v[1] = (__bf16)b;
  return __builtin_bit_cast(unsigned, v);
}

// ---------------------------------------------------------------------------
// Pass 1: Cm[p][k] = bf16( cos(pi*(2P[p]+1)*k/16384) * w[k] * D[k] )
// ---------------------------------------------------------------------------
__global__ __launch_bounds__(256) void build_c_kernel(
    const int* __restrict__ Pp, const float* __restrict__ Dp,
    unsigned short* __restrict__ Cm) {
  const int p = blockIdx.x;
  const int n2 = 2 * Pp[p] + 1;
  const int t = threadIdx.x;
#pragma unroll
  for (int ch = 0; ch < 4; ++ch) {
    const int kb = (ch << 11) + (t << 3);
    u16x8 o;
#pragma unroll
    for (int i = 0; i < 8; ++i) {
      const int k = kb + i;
      const unsigned tt = ((unsigned)(n2 * k)) & 32767u;
      const float cv = cosf((float)tt * 1.9174759848570515e-4f);  // pi/16384
      const float wk = (k == 0) ? (0.5f / 8192.0f) : (1.0f / 8192.0f);
      o[i] = f2bf(cv * wk * Dp[k]);
    }
    *(u16x8*)(Cm + ((size_t)p << 13) + kb) = o;
  }
}

// ---------------------------------------------------------------------------
// Pass 2: GEMM  part[bz] = Cm[1024x8192] @ M  (B = M consumed directly, f32)
// BM=BN=256, BK=64, 512 thr (2Mx4N waves).  Verified R5/R6 maps; K-loop uses
// counted-vmcnt pipeline: B loads 2 tiles ahead (sbA/sbB static rotation),
// stageA(t+1) issued BEFORE loadB(t+2) so tile-end vmcnt(8) drains exactly
// A(t+1) and keeps the 8 B(t+2) loads in flight across the barrier (T4).
// ---------------------------------------------------------------------------
__global__ __launch_bounds__(512, 1) void gemm_kernel(
    const unsigned short* __restrict__ Cm, const float* __restrict__ Mp,
    float* __restrict__ outp, int kchunk, int nwg) {
  __shared__ __align__(16) char lds[2 * BUFSZ];

  // XCD-aware bijective swizzle; bm-major so each XCD chunk reuses B panels
  const int id = blockIdx.x;
  const int chunk = nwg >> 3;
  const int sid = (id & 7) * chunk + (id >> 3);
  const int bm = sid & 3, bn = (sid >> 2) & 15, bz = sid >> 6;

  const int t = threadIdx.x;
  const int w = t >> 6, l = t & 63;
  const int wr = w >> 2, wc = w & 3;
  const int lg = l >> 4, lr = l & 15;
  const int k_begin = bz * kchunk;
  const int NT = kchunk >> 6;   // 32 for ksplit=4 (even: tt+=2 rotation valid)

  // ---- A staging: global_load_lds, source col pre-swizzled (LDS linear)
  const int arow = t >> 3;
  const int acol = ((t & 7) << 4) ^ ((arow & 7) << 4);
  const char* Agl = (const char*)Cm + ((size_t)(bm * 256 + arow) << 14) +
                    ((size_t)k_begin << 1) + acol;
  auto stageA = [&](int nbuf, int tile) {
    char* d = (char*)lds + nbuf * BUFSZ + t * 16;
    const char* s = Agl + ((size_t)tile << 7);
#pragma unroll
    for (int i = 0; i < 4; ++i)
      __builtin_amdgcn_global_load_lds(
          (const __attribute__((address_space(1))) void*)(s + ((size_t)i << 20)),
          (__attribute__((address_space(3))) void*)(d + i * 8192), 16, 0, 0);
  };

  // ---- B staging: thread t handles k = w*8 + (0..7), n = (t&63)*4 + nn
  const float* Bg = Mp + (size_t)k_begin * N_OUT + bn * 256 + l * 4;
  auto loadB = [&](f32x4 (&r)[8], int tile) {
#pragma unroll
    for (int i = 0; i < 8; ++i)
      r[i] = *(const f32x4*)(Bg + (size_t)(tile * 64 + w * 8 + i) * N_OUT);
  };
  auto writeB = [&](const f32x4 (&r)[8], int nbuf) {
#pragma unroll
    for (int nn = 0; nn < 4; ++nn) {
      const int n = (l << 2) + nn;
      const int sN = (n & 7) ^ ((n >> 2) & 7);
      u32x4 pk;
#pragma unroll
      for (int j = 0; j < 4; ++j) pk[j] = pack2(r[2 * j][nn], r[2 * j + 1][nn]);
      *(u32x4*)(lds + nbuf * BUFSZ + 32768 + n * 128 + ((w ^ sN) << 4)) = pk;
    }
  };

  // ---- fragment read offsets
  const int sw = (lr & 7) << 4;
  const int xk0 = (lg << 4) ^ sw;
  const int xk1 = (64 + (lg << 4)) ^ sw;
  unsigned boff[2][4];
#pragma unroll
  for (int kk = 0; kk < 2; ++kk)
#pragma unroll
    for (int nf = 0; nf < 4; ++nf) {
      const int row = wc * 64 + nf * 16 + lr;
      const int sN = (row & 7) ^ ((row >> 2) & 7);
      boff[kk][nf] = 32768 + row * 128 + ((((kk << 2) | lg) ^ sN) << 4);
    }

  f32x4 acc[8][4] = {};
  bf16x8 Af[4];
  bf16x8 Bf[4];

  auto readA = [&](const char* aBuf, int mh, int xk) {
#pragma unroll
    for (int m = 0; m < 4; ++m)
      Af[m] = *(const bf16x8*)(aBuf + mh * 8192 + m * 2048 + xk);
  };
  auto readB = [&](int nbuf, int kk) {
#pragma unroll
    for (int nf = 0; nf < 4; ++nf)
      Bf[nf] = *(const bf16x8*)(lds + nbuf * BUFSZ + boff[kk][nf]);
  };
  auto mm = [&](int mh) {
    __builtin_amdgcn_s_setprio(1);
#pragma unroll
    for (int m = 0; m < 4; ++m)
#pragma unroll
      for (int nf = 0; nf < 4; ++nf)
        acc[mh * 4 + m][nf] = __builtin_amdgcn_mfma_f32_16x16x32_bf16(
            Af[m], Bf[nf], acc[mh * 4 + m][nf], 0, 0, 0);
    __builtin_amdgcn_s_setprio(0);
  };

  f32x4 sbA[8], sbB[8];

  // ---- prologue: A(0)+B(0) -> buf0 (B(0) staged via sbA); preload sbB = B(1)
  {
    stageA(0, 0);       // 4 ops (oldest)
    loadB(sbA, 0);      // 8 ops
    loadB(sbB, 1);      // 8 ops (newest)
    writeB(sbA, 0);     // compiler drains sbA loads (vmcnt(8), sbB stays out)
    asm volatile("s_waitcnt vmcnt(8) lgkmcnt(0)" ::: "memory");  // A(0) resident
    __builtin_amdgcn_sched_barrier(0);
    __builtin_amdgcn_s_barrier();
  }

  // tile body: even tiles load sbA (data t+2) / write sbB (data t+1); odd swap
  auto tile_body = [&](int tt, f32x4 (&sbLoad)[8], f32x4 (&sbWrite)[8]) {
    const int cur = tt & 1, nxt = cur ^ 1;
    const char* aBuf = (const char*)lds + cur * BUFSZ + wr * 16384 + lr * 128;
    const bool more1 = (tt + 1) < NT;
    const bool more2 = (tt + 2) < NT;
    // ---- ph1: stage A(t+1) (must precede loadB for in-order vmcnt count)
    if (more1) stageA(nxt, tt + 1);
    readB(cur, 0);
    readA(aBuf, 0, xk0);
    __builtin_amdgcn_s_barrier();
    mm(0);
    __builtin_amdgcn_s_barrier();
    // ---- ph2: issue B(t+2) loads (the 8 newest VMEM ops at tile end)
    if (more2) loadB(sbLoad, tt + 2);
    readA(aBuf, 1, xk0);
    __builtin_amdgcn_s_barrier();
    mm(1);
    __builtin_amdgcn_s_barrier();
    // ---- ph3: write B(t+1) (data loaded 2 tiles ago; non-draining wait)
    readB(cur, 1);
    readA(aBuf, 0, xk1);
    if (more1) writeB(sbWrite, nxt);
    __builtin_amdgcn_s_barrier();
    mm(0);
    __builtin_amdgcn_s_barrier();
    // ---- ph4
    readA(aBuf, 1, xk1);
    __builtin_amdgcn_s_barrier();
    mm(1);
    // counted tile-end drain: A(t+1) resident, B(t+2) stays in flight
    if (more2) { asm volatile("s_waitcnt vmcnt(8)" ::: "memory"); }
    else       { asm volatile("s_waitcnt vmcnt(0)" ::: "memory"); }
    asm volatile("s_waitcnt lgkmcnt(0)" ::: "memory");
    __builtin_amdgcn_sched_barrier(0);
    __builtin_amdgcn_s_barrier();
  };

  for (int tt = 0; tt < NT; tt += 2) {
    tile_body(tt, sbA, sbB);
    tile_body(tt + 1, sbB, sbA);
  }

  // ---- epilogue
  float* po = outp + (size_t)bz * (M_OUT * N_OUT);
  const int orow = bm * 256 + wr * 128;
  const int ocol = bn * 256 + wc * 64 + lr;
#pragma unroll
  for (int mi = 0; mi < 8; ++mi) {
    const int r0 = orow + (mi >> 2) * 64 + (mi & 3) * 16 + (lg << 2);
#pragma unroll
    for (int ni = 0; ni < 4; ++ni) {
      const int c = ocol + ni * 16;
#pragma unroll
      for (int q = 0; q < 4; ++q)
        po[(size_t)(r0 + q) * N_OUT + c] = acc[mi][ni][q];
    }
  }
}

// ---------------------------------------------------------------------------
// Pass 3: reduce K-split partials
// ---------------------------------------------------------------------------
__global__ __launch_bounds__(256) void reduce_kernel(
    const float* __restrict__ part, float* __restrict__ out, int ksplit) {
  const size_t total = (size_t)M_OUT * N_OUT;
  const size_t i = ((size_t)blockIdx.x * 256 + threadIdx.x) * 4;
  if (i >= total) return;
  f32x4 s = *(const f32x4*)(part + i);
  for (int s2 = 1; s2 < ksplit; ++s2) s += *(const f32x4*)(part + (size_t)s2 * total + i);
  *(f32x4*)(out + i) = s;
}

// ---------------------------------------------------------------------------
// Fallback: direct f32 evaluation
// ---------------------------------------------------------------------------
__global__ __launch_bounds__(256) void naive_kernel(
    const float* __restrict__ Mp, const float* __restrict__ Dp,
    const int* __restrict__ Pp, float* __restrict__ out) {
  const int p = blockIdx.y;
  const int j = blockIdx.x * 256 + threadIdx.x;
  const int n2 = 2 * Pp[p] + 1;
  float acc = 0.0f;
  for (int k = 0; k < K_DIM; ++k) {
    const unsigned tt = ((unsigned)(n2 * k)) & 32767u;
    const float cv = cosf((float)tt * 1.9174759848570515e-4f);
    const float wk = (k == 0) ? 0.5f : 1.0f;
    acc += cv * wk * Dp[k] * Mp[(size_t)k * N_OUT + j];
  }
  out[(size_t)p * N_OUT + j] = acc * (1.0f / 8192.0f);
}

extern "C" void kernel_launch(void* const* d_in, const int* in_sizes, int n_in,
                              void* d_out, int out_size, void* d_ws, size_t ws_size,
                              hipStream_t stream) {
  const float* Mp = (const float*)d_in[0];
  const float* Dp = (const float*)d_in[1];
  const int* Pp = (const int*)d_in[2];
  float* out = (float*)d_out;

  const size_t CM_BYTES = (size_t)M_OUT * K_DIM * 2;       // 16 MiB
  const size_t PART_BYTES = (size_t)M_OUT * N_OUT * 4;     // 16 MiB per split

  int ksplit;
  if (ws_size >= CM_BYTES + 4 * PART_BYTES) ksplit = 4;
  else if (ws_size >= CM_BYTES + 2 * PART_BYTES) ksplit = 2;
  else if (ws_size >= CM_BYTES) ksplit = 1;
  else ksplit = 0;

  if (ksplit == 0) {
    naive_kernel<<<dim3(N_OUT / 256, M_OUT), 256, 0, stream>>>(Mp, Dp, Pp, out);
    return;
  }

  unsigned short* Cm = (unsigned short*)d_ws;
  float* part = (float*)((char*)d_ws + CM_BYTES);

  build_c_kernel<<<dim3(M_OUT), 256, 0, stream>>>(Pp, Dp, Cm);

  float* gout = (ksplit > 1) ? part : out;
  const int kchunk = K_DIM / ksplit;
  const int nwg = 64 * ksplit;
  gemm_kernel<<<dim3(nwg), 512, 0, stream>>>(Cm, Mp, gout, kchunk, nwg);

  if (ksplit > 1)
    reduce_kernel<<<dim3((M_OUT * N_OUT / 4 + 255) / 256), 256, 0, stream>>>(part, out, ksplit);
}

// Round 11
// 118.233 us; speedup vs baseline: 2.6760x; 2.6760x over previous
//
#include <hip/hip_runtime.h>

#define K_DIM 8192
#define M_OUT 1024
#define N_OUT 4096
#define BUFSZ 32768   // per-dbuf LDS: A 16 KiB + B 16 KiB

typedef __attribute__((ext_vector_type(4))) float f32x4;
typedef __attribute__((ext_vector_type(8))) __bf16 bf16x8;
typedef __attribute__((ext_vector_type(2))) __bf16 bf16x2;
typedef __attribute__((ext_vector_type(4))) unsigned u32x4;
typedef __attribute__((ext_vector_type(8))) unsigned short u16x8;

__device__ __forceinline__ unsigned short f2bf(float x) {
  unsigned u = __builtin_bit_cast(unsigned, x);
  u += 0x7fffu + ((u >> 16) & 1u);   // round-to-nearest-even
  return (unsigned short)(u >> 16);
}

__device__ __forceinline__ unsigned pack2(float a, float b) {
  bf16x2 v;
  v[0] = (__bf16)a;   // RNE; pairs lower to v_cvt_pk_bf16_f32
  v[1] = (__bf16)b;
  return __builtin_bit_cast(unsigned, v);
}

// ---------------------------------------------------------------------------
// Pass 1: Cm[p][k] = bf16( cos(pi*(2P[p]+1)*k/16384) * w[k] * D[k] )
// ---------------------------------------------------------------------------
__global__ __launch_bounds__(256) void build_c_kernel(
    const int* __restrict__ Pp, const float* __restrict__ Dp,
    unsigned short* __restrict__ Cm) {
  const int p = blockIdx.x;
  const int n2 = 2 * Pp[p] + 1;
  const int t = threadIdx.x;
#pragma unroll
  for (int ch = 0; ch < 4; ++ch) {
    const int kb = (ch << 11) + (t << 3);
    u16x8 o;
#pragma unroll
    for (int i = 0; i < 8; ++i) {
      const int k = kb + i;
      const unsigned tt = ((unsigned)(n2 * k)) & 32767u;
      const float cv = cosf((float)tt * 1.9174759848570515e-4f);  // pi/16384
      const float wk = (k == 0) ? (0.5f / 8192.0f) : (1.0f / 8192.0f);
      o[i] = f2bf(cv * wk * Dp[k]);
    }
    *(u16x8*)(Cm + ((size_t)p << 13) + kb) = o;
  }
}

// ---------------------------------------------------------------------------
// Pass 2: GEMM  part[bz] = Cm[1024x8192] @ M.  BM=BN=128, BK=64,
// 256 thr = 4 waves (2x2), per-wave out 64x64.  LDS 64 KiB -> 2 INDEPENDENT
// blocks/CU (m114 overlap across blocks replaces intra-block pipelining).
// Maps are the R5/R6-verified formulas re-parameterized (conflict-free).
// ---------------------------------------------------------------------------
__global__ __launch_bounds__(256, 2) void gemm_kernel(
    const unsigned short* __restrict__ Cm, const float* __restrict__ Mp,
    float* __restrict__ outp, int kchunk, int nwg) {
  __shared__ __align__(16) char lds[2 * BUFSZ];

  // XCD-aware bijective swizzle; (bz,bm) fastest so blocks sharing a B panel
  // (same bn) land in the same XCD chunk (chunk=64 = 4 bn panels).
  const int id = blockIdx.x;
  const int chunk = nwg >> 3;
  const int sid = (id & 7) * chunk + (id >> 3);
  const int bz = sid & 1, bm = (sid >> 1) & 7, bn = sid >> 4;

  const int t = threadIdx.x;
  const int w = t >> 6, l = t & 63;
  const int wr = w >> 1, wc = w & 1;          // 2M x 2N waves
  const int lg = l >> 4, lr = l & 15;
  const int k_begin = bz * kchunk;
  const int NT = kchunk >> 6;                 // 64 for ksplit=2

  // ---- A staging: global_load_lds, source col pre-swizzled (LDS linear)
  const int arow = t >> 3;                    // 0..31
  const int acol = ((t & 7) << 4) ^ ((arow & 7) << 4);
  const char* Agl = (const char*)Cm + ((size_t)(bm * 128 + arow) << 14) +
                    ((size_t)k_begin << 1) + acol;
  auto stageA = [&](int nbuf, int tile) {
    char* d = (char*)lds + nbuf * BUFSZ + t * 16;
    const char* s = Agl + ((size_t)tile << 7);
#pragma unroll
    for (int i = 0; i < 4; ++i)   // rows i*32..: global stride 32*16384 B
      __builtin_amdgcn_global_load_lds(
          (const __attribute__((address_space(1))) void*)(s + ((size_t)i << 19)),
          (__attribute__((address_space(3))) void*)(d + i * 4096), 16, 0, 0);
  };

  // ---- B staging: thread t covers k-oct = t>>5 (k = (t>>5)*8 + 0..7),
  //                 n = (t&31)*4 + nn    (same per-thread shape as R6)
  const int bk0 = (t >> 5) * 8;
  const int bn0 = (t & 31) * 4;
  const float* Bg = Mp + (size_t)k_begin * N_OUT + bn * 128 + bn0;
  auto loadB = [&](f32x4 (&r)[8], int tile) {
#pragma unroll
    for (int i = 0; i < 8; ++i)
      r[i] = *(const f32x4*)(Bg + (size_t)(tile * 64 + bk0 + i) * N_OUT);
  };
  auto writeB = [&](const f32x4 (&r)[8], int nbuf) {
#pragma unroll
    for (int nn = 0; nn < 4; ++nn) {
      const int n = bn0 + nn;
      const int sN = (n & 7) ^ ((n >> 2) & 7);
      u32x4 pk;
#pragma unroll
      for (int j = 0; j < 4; ++j) pk[j] = pack2(r[2 * j][nn], r[2 * j + 1][nn]);
      *(u32x4*)(lds + nbuf * BUFSZ + 16384 + n * 128 +
                (((t >> 5) ^ sN) << 4)) = pk;
    }
  };

  // ---- fragment read offsets (R6-verified formulas)
  const int sw = (lr & 7) << 4;
  const int xk0 = (lg << 4) ^ sw;
  const int xk1 = (64 + (lg << 4)) ^ sw;
  unsigned boff[2][4];
#pragma unroll
  for (int kk = 0; kk < 2; ++kk)
#pragma unroll
    for (int nf = 0; nf < 4; ++nf) {
      const int row = wc * 64 + nf * 16 + lr;
      const int sN = (row & 7) ^ ((row >> 2) & 7);
      boff[kk][nf] = 16384 + row * 128 + ((((kk << 2) | lg) ^ sN) << 4);
    }

  f32x4 acc[4][4] = {};
  bf16x8 Af[4];
  bf16x8 Bf[4];

  auto readA = [&](int nbuf, int xk) {
    const char* aBuf = (const char*)lds + nbuf * BUFSZ + wr * 8192 + lr * 128;
#pragma unroll
    for (int m = 0; m < 4; ++m)
      Af[m] = *(const bf16x8*)(aBuf + m * 2048 + xk);
  };
  auto readB = [&](int nbuf, int kk) {
#pragma unroll
    for (int nf = 0; nf < 4; ++nf)
      Bf[nf] = *(const bf16x8*)(lds + nbuf * BUFSZ + boff[kk][nf]);
  };
  auto mm = [&]() {
#pragma unroll
    for (int m = 0; m < 4; ++m)
#pragma unroll
      for (int nf = 0; nf < 4; ++nf)
        acc[m][nf] = __builtin_amdgcn_mfma_f32_16x16x32_bf16(
            Af[m], Bf[nf], acc[m][nf], 0, 0, 0);
  };

  // ---- prologue: tile 0 into buf 0
  {
    f32x4 p[8];
    stageA(0, 0);
    loadB(p, 0);
    writeB(p, 0);
    asm volatile("s_waitcnt vmcnt(0) lgkmcnt(0)" ::: "memory");
    __builtin_amdgcn_sched_barrier(0);
    __builtin_amdgcn_s_barrier();
  }

  for (int tt = 0; tt < NT; ++tt) {
    const int cur = tt & 1, nxt = cur ^ 1;
    const bool more = (tt + 1) < NT;
    f32x4 sb[8];
    if (more) {
      loadB(sb, tt + 1);
      stageA(nxt, tt + 1);
    }
    // kk0
    readB(cur, 0);
    readA(cur, xk0);
    mm();
    // mid-tile: write next tile's B (compiler inserts counted vmcnt for sb)
    if (more) writeB(sb, nxt);
    // kk1
    readB(cur, 1);
    readA(cur, xk1);
    mm();
    asm volatile("s_waitcnt vmcnt(0) lgkmcnt(0)" ::: "memory");
    __builtin_amdgcn_sched_barrier(0);
    __builtin_amdgcn_s_barrier();
  }

  // ---- epilogue
  float* po = outp + (size_t)bz * (M_OUT * N_OUT);
  const int orow = bm * 128 + wr * 64;
  const int ocol = bn * 128 + wc * 64 + lr;
#pragma unroll
  for (int m = 0; m < 4; ++m) {
    const int r0 = orow + m * 16 + (lg << 2);
#pragma unroll
    for (int nf = 0; nf < 4; ++nf) {
      const int c = ocol + nf * 16;
#pragma unroll
      for (int q = 0; q < 4; ++q)
        po[(size_t)(r0 + q) * N_OUT + c] = acc[m][nf][q];
    }
  }
}

// ---------------------------------------------------------------------------
// Pass 3: reduce K-split partials
// ---------------------------------------------------------------------------
__global__ __launch_bounds__(256) void reduce_kernel(
    const float* __restrict__ part, float* __restrict__ out, int ksplit) {
  const size_t total = (size_t)M_OUT * N_OUT;
  const size_t i = ((size_t)blockIdx.x * 256 + threadIdx.x) * 4;
  if (i >= total) return;
  f32x4 s = *(const f32x4*)(part + i);
  for (int s2 = 1; s2 < ksplit; ++s2) s += *(const f32x4*)(part + (size_t)s2 * total + i);
  *(f32x4*)(out + i) = s;
}

// ---------------------------------------------------------------------------
// Fallback: direct f32 evaluation
// ---------------------------------------------------------------------------
__global__ __launch_bounds__(256) void naive_kernel(
    const float* __restrict__ Mp, const float* __restrict__ Dp,
    const int* __restrict__ Pp, float* __restrict__ out) {
  const int p = blockIdx.y;
  const int j = blockIdx.x * 256 + threadIdx.x;
  const int n2 = 2 * Pp[p] + 1;
  float acc = 0.0f;
  for (int k = 0; k < K_DIM; ++k) {
    const unsigned tt = ((unsigned)(n2 * k)) & 32767u;
    const float cv = cosf((float)tt * 1.9174759848570515e-4f);
    const float wk = (k == 0) ? 0.5f : 1.0f;
    acc += cv * wk * Dp[k] * Mp[(size_t)k * N_OUT + j];
  }
  out[(size_t)p * N_OUT + j] = acc * (1.0f / 8192.0f);
}

extern "C" void kernel_launch(void* const* d_in, const int* in_sizes, int n_in,
                              void* d_out, int out_size, void* d_ws, size_t ws_size,
                              hipStream_t stream) {
  const float* Mp = (const float*)d_in[0];
  const float* Dp = (const float*)d_in[1];
  const int* Pp = (const int*)d_in[2];
  float* out = (float*)d_out;

  const size_t CM_BYTES = (size_t)M_OUT * K_DIM * 2;       // 16 MiB
  const size_t PART_BYTES = (size_t)M_OUT * N_OUT * 4;     // 16 MiB per split

  int ksplit;
  if (ws_size >= CM_BYTES + 2 * PART_BYTES) ksplit = 2;
  else if (ws_size >= CM_BYTES) ksplit = 1;
  else ksplit = 0;

  if (ksplit == 0) {
    naive_kernel<<<dim3(N_OUT / 256, M_OUT), 256, 0, stream>>>(Mp, Dp, Pp, out);
    return;
  }

  unsigned short* Cm = (unsigned short*)d_ws;
  float* part = (float*)((char*)d_ws + CM_BYTES);

  build_c_kernel<<<dim3(M_OUT), 256, 0, stream>>>(Pp, Dp, Cm);

  float* gout = (ksplit > 1) ? part : out;
  const int kchunk = K_DIM / ksplit;
  const int nwg = (M_OUT / 128) * (N_OUT / 128) * ksplit;   // 512 for ksplit=2
  gemm_kernel<<<dim3(nwg), 256, 0, stream>>>(Cm, Mp, gout, kchunk, nwg);

  if (ksplit > 1)
    reduce_kernel<<<dim3((M_OUT * N_OUT / 4 + 255) / 256), 256, 0, stream>>>(part, out, ksplit);
}

// Round 12
// 102.361 us; speedup vs baseline: 3.0909x; 1.1551x over previous
//
#include <hip/hip_runtime.h>

#define K_DIM 8192
#define M_OUT 1024
#define N_OUT 4096
#define BUFSZ 65536   // per-dbuf LDS: A 32 KiB + B 32 KiB

typedef __attribute__((ext_vector_type(4))) float f32x4;
typedef __attribute__((ext_vector_type(8))) __bf16 bf16x8;
typedef __attribute__((ext_vector_type(2))) __bf16 bf16x2;
typedef __attribute__((ext_vector_type(4))) unsigned u32x4;
typedef __attribute__((ext_vector_type(4))) unsigned short u16x4;
typedef __attribute__((ext_vector_type(8))) unsigned short u16x8;

__device__ __forceinline__ unsigned short f2bf(float x) {
  unsigned u = __builtin_bit_cast(unsigned, x);
  u += 0x7fffu + ((u >> 16) & 1u);   // round-to-nearest-even
  return (unsigned short)(u >> 16);
}

__device__ __forceinline__ unsigned pack2(float a, float b) {
  bf16x2 v;
  v[0] = (__bf16)a;   // RNE; pairs lower to v_cvt_pk_bf16_f32
  v[1] = (__bf16)b;
  return __builtin_bit_cast(unsigned, v);
}

__device__ __forceinline__ float bf2f(unsigned short h) {
  unsigned u = ((unsigned)h) << 16;
  return __builtin_bit_cast(float, u);
}

// ---------------------------------------------------------------------------
// Pass 1: Cm[p][k] = bf16( cos(pi*(2P[p]+1)*k/16384) * w[k] * D[k] )
// ---------------------------------------------------------------------------
__global__ __launch_bounds__(256) void build_c_kernel(
    const int* __restrict__ Pp, const float* __restrict__ Dp,
    unsigned short* __restrict__ Cm) {
  const int p = blockIdx.x;
  const int n2 = 2 * Pp[p] + 1;
  const int t = threadIdx.x;
#pragma unroll
  for (int ch = 0; ch < 4; ++ch) {
    const int kb = (ch << 11) + (t << 3);
    u16x8 o;
#pragma unroll
    for (int i = 0; i < 8; ++i) {
      const int k = kb + i;
      const unsigned tt = ((unsigned)(n2 * k)) & 32767u;
      const float cv = cosf((float)tt * 1.9174759848570515e-4f);  // pi/16384
      const float wk = (k == 0) ? (0.5f / 8192.0f) : (1.0f / 8192.0f);
      o[i] = f2bf(cv * wk * Dp[k]);
    }
    *(u16x8*)(Cm + ((size_t)p << 13) + kb) = o;
  }
}

// ---------------------------------------------------------------------------
// Pass 2: GEMM  part[bz] = Cm[1024x8192] @ M  (B = M consumed directly, f32)
// BM=BN=256, BK=64, 512 thr (2Mx4N waves).  R6-verified loop (drain-0).
// Epilogue: bf16 partials when ksplit>1 (halves reduce traffic), f32 direct
// when ksplit==1.
// ---------------------------------------------------------------------------
__global__ __launch_bounds__(512, 1) void gemm_kernel(
    const unsigned short* __restrict__ Cm, const float* __restrict__ Mp,
    float* __restrict__ outf, unsigned short* __restrict__ outh,
    int kchunk, int nwg) {
  __shared__ __align__(16) char lds[2 * BUFSZ];

  // XCD-aware bijective swizzle; bm-major so each XCD chunk reuses B panels
  const int id = blockIdx.x;
  const int chunk = nwg >> 3;
  const int sid = (id & 7) * chunk + (id >> 3);
  const int bm = sid & 3, bn = (sid >> 2) & 15, bz = sid >> 6;

  const int t = threadIdx.x;
  const int w = t >> 6, l = t & 63;
  const int wr = w >> 2, wc = w & 3;
  const int lg = l >> 4, lr = l & 15;
  const int k_begin = bz * kchunk;
  const int NT = kchunk >> 6;

  // ---- A staging: global_load_lds, source col pre-swizzled (LDS linear)
  const int arow = t >> 3;
  const int acol = ((t & 7) << 4) ^ ((arow & 7) << 4);
  const char* Agl = (const char*)Cm + ((size_t)(bm * 256 + arow) << 14) +
                    ((size_t)k_begin << 1) + acol;
  auto stageA = [&](int nbuf, int tile) {
    char* d = (char*)lds + nbuf * BUFSZ + t * 16;
    const char* s = Agl + ((size_t)tile << 7);
#pragma unroll
    for (int i = 0; i < 4; ++i)
      __builtin_amdgcn_global_load_lds(
          (const __attribute__((address_space(1))) void*)(s + ((size_t)i << 20)),
          (__attribute__((address_space(3))) void*)(d + i * 8192), 16, 0, 0);
  };

  // ---- B staging: thread t handles k = w*8 + (0..7), n = (t&63)*4 + nn
  const float* Bg = Mp + (size_t)k_begin * N_OUT + bn * 256 + l * 4;
  auto loadB = [&](f32x4 (&r)[8], int tile, int half) {
#pragma unroll
    for (int i = 0; i < 4; ++i)
      r[half * 4 + i] =
          *(const f32x4*)(Bg + (size_t)(tile * 64 + w * 8 + half * 4 + i) * N_OUT);
  };
  auto writeB = [&](const f32x4 (&r)[8], int nbuf, int nn) {
    const int n = (l << 2) + nn;
    const int sN = (n & 7) ^ ((n >> 2) & 7);
    u32x4 pk;
#pragma unroll
    for (int j = 0; j < 4; ++j) pk[j] = pack2(r[2 * j][nn], r[2 * j + 1][nn]);
    *(u32x4*)(lds + nbuf * BUFSZ + 32768 + n * 128 + ((w ^ sN) << 4)) = pk;
  };

  // ---- fragment read offsets
  const int sw = (lr & 7) << 4;
  const int xk0 = (lg << 4) ^ sw;
  const int xk1 = (64 + (lg << 4)) ^ sw;
  unsigned boff[2][4];
#pragma unroll
  for (int kk = 0; kk < 2; ++kk)
#pragma unroll
    for (int nf = 0; nf < 4; ++nf) {
      const int row = wc * 64 + nf * 16 + lr;
      const int sN = (row & 7) ^ ((row >> 2) & 7);
      boff[kk][nf] = 32768 + row * 128 + ((((kk << 2) | lg) ^ sN) << 4);
    }

  f32x4 acc[8][4] = {};
  bf16x8 Af[4];
  bf16x8 Bf[4];

  auto readA = [&](const char* aBuf, int mh, int xk) {
#pragma unroll
    for (int m = 0; m < 4; ++m)
      Af[m] = *(const bf16x8*)(aBuf + mh * 8192 + m * 2048 + xk);
  };
  auto readB = [&](int nbuf, int kk) {
#pragma unroll
    for (int nf = 0; nf < 4; ++nf)
      Bf[nf] = *(const bf16x8*)(lds + nbuf * BUFSZ + boff[kk][nf]);
  };
  auto mm = [&](int mh) {
    __builtin_amdgcn_s_setprio(1);
#pragma unroll
    for (int m = 0; m < 4; ++m)
#pragma unroll
      for (int nf = 0; nf < 4; ++nf)
        acc[mh * 4 + m][nf] = __builtin_amdgcn_mfma_f32_16x16x32_bf16(
            Af[m], Bf[nf], acc[mh * 4 + m][nf], 0, 0, 0);
    __builtin_amdgcn_s_setprio(0);
  };

  // ---- prologue: tile 0 into buf 0
  {
    f32x4 p[8];
    stageA(0, 0);
    loadB(p, 0, 0);
    loadB(p, 0, 1);
#pragma unroll
    for (int nn = 0; nn < 4; ++nn) writeB(p, 0, nn);
    asm volatile("s_waitcnt vmcnt(0) lgkmcnt(0)" ::: "memory");
    __builtin_amdgcn_sched_barrier(0);
    __builtin_amdgcn_s_barrier();
  }

  for (int tt = 0; tt < NT; ++tt) {
    const int cur = tt & 1, nxt = cur ^ 1;
    const char* aBuf = (const char*)lds + cur * BUFSZ + wr * 16384 + lr * 128;
    const bool more = (tt + 1) < NT;
    f32x4 sb[8];
    if (more) {
      loadB(sb, tt + 1, 0);
      loadB(sb, tt + 1, 1);
      stageA(nxt, tt + 1);
    }
    // kk0
    readB(cur, 0);
    readA(aBuf, 0, xk0);
    mm(0);
    readA(aBuf, 1, xk0);
    mm(1);
    if (more) {
      writeB(sb, nxt, 0);
      writeB(sb, nxt, 1);
      writeB(sb, nxt, 2);
      writeB(sb, nxt, 3);
    }
    // kk1
    readB(cur, 1);
    readA(aBuf, 0, xk1);
    mm(0);
    readA(aBuf, 1, xk1);
    mm(1);
    asm volatile("s_waitcnt vmcnt(0) lgkmcnt(0)" ::: "memory");
    __builtin_amdgcn_sched_barrier(0);
    __builtin_amdgcn_s_barrier();
  }

  // ---- epilogue
  const int orow = bm * 256 + wr * 128;
  const int ocol = bn * 256 + wc * 64 + lr;
  if (outh) {
    unsigned short* po = outh + (size_t)bz * (M_OUT * N_OUT);
#pragma unroll
    for (int mi = 0; mi < 8; ++mi) {
      const int r0 = orow + (mi >> 2) * 64 + (mi & 3) * 16 + (lg << 2);
#pragma unroll
      for (int ni = 0; ni < 4; ++ni) {
        const int c = ocol + ni * 16;
#pragma unroll
        for (int q = 0; q < 4; ++q)
          po[(size_t)(r0 + q) * N_OUT + c] = f2bf(acc[mi][ni][q]);
      }
    }
  } else {
#pragma unroll
    for (int mi = 0; mi < 8; ++mi) {
      const int r0 = orow + (mi >> 2) * 64 + (mi & 3) * 16 + (lg << 2);
#pragma unroll
      for (int ni = 0; ni < 4; ++ni) {
        const int c = ocol + ni * 16;
#pragma unroll
        for (int q = 0; q < 4; ++q)
          outf[(size_t)(r0 + q) * N_OUT + c] = acc[mi][ni][q];
      }
    }
  }
}

// ---------------------------------------------------------------------------
// Pass 3: reduce bf16 K-split partials -> f32 out
// ---------------------------------------------------------------------------
__global__ __launch_bounds__(256) void reduce_kernel(
    const unsigned short* __restrict__ part, float* __restrict__ out,
    int ksplit) {
  const size_t total = (size_t)M_OUT * N_OUT;
  const size_t i = ((size_t)blockIdx.x * 256 + threadIdx.x) * 8;
  if (i >= total) return;
  float s[8];
#pragma unroll
  for (int j = 0; j < 8; ++j) s[j] = 0.0f;
  for (int s2 = 0; s2 < ksplit; ++s2) {
    u16x8 v = *(const u16x8*)(part + (size_t)s2 * total + i);
#pragma unroll
    for (int j = 0; j < 8; ++j) s[j] += bf2f(v[j]);
  }
  f32x4 o0, o1;
#pragma unroll
  for (int j = 0; j < 4; ++j) { o0[j] = s[j]; o1[j] = s[4 + j]; }
  *(f32x4*)(out + i) = o0;
  *(f32x4*)(out + i + 4) = o1;
}

// ---------------------------------------------------------------------------
// Fallback: direct f32 evaluation
// ---------------------------------------------------------------------------
__global__ __launch_bounds__(256) void naive_kernel(
    const float* __restrict__ Mp, const float* __restrict__ Dp,
    const int* __restrict__ Pp, float* __restrict__ out) {
  const int p = blockIdx.y;
  const int j = blockIdx.x * 256 + threadIdx.x;
  const int n2 = 2 * Pp[p] + 1;
  float acc = 0.0f;
  for (int k = 0; k < K_DIM; ++k) {
    const unsigned tt = ((unsigned)(n2 * k)) & 32767u;
    const float cv = cosf((float)tt * 1.9174759848570515e-4f);
    const float wk = (k == 0) ? 0.5f : 1.0f;
    acc += cv * wk * Dp[k] * Mp[(size_t)k * N_OUT + j];
  }
  out[(size_t)p * N_OUT + j] = acc * (1.0f / 8192.0f);
}

extern "C" void kernel_launch(void* const* d_in, const int* in_sizes, int n_in,
                              void* d_out, int out_size, void* d_ws, size_t ws_size,
                              hipStream_t stream) {
  const float* Mp = (const float*)d_in[0];
  const float* Dp = (const float*)d_in[1];
  const int* Pp = (const int*)d_in[2];
  float* out = (float*)d_out;

  const size_t CM_BYTES = (size_t)M_OUT * K_DIM * 2;       // 16 MiB
  const size_t PART_BYTES = (size_t)M_OUT * N_OUT * 2;     // 8 MiB per split (bf16)

  int ksplit;
  if (ws_size >= CM_BYTES + 4 * PART_BYTES) ksplit = 4;
  else if (ws_size >= CM_BYTES + 2 * PART_BYTES) ksplit = 2;
  else if (ws_size >= CM_BYTES) ksplit = 1;
  else ksplit = 0;

  if (ksplit == 0) {
    naive_kernel<<<dim3(N_OUT / 256, M_OUT), 256, 0, stream>>>(Mp, Dp, Pp, out);
    return;
  }

  unsigned short* Cm = (unsigned short*)d_ws;
  unsigned short* part = (unsigned short*)((char*)d_ws + CM_BYTES);

  build_c_kernel<<<dim3(M_OUT), 256, 0, stream>>>(Pp, Dp, Cm);

  const int kchunk = K_DIM / ksplit;
  const int nwg = 64 * ksplit;
  gemm_kernel<<<dim3(nwg), 512, 0, stream>>>(
      Cm, Mp, (ksplit > 1) ? nullptr : out, (ksplit > 1) ? part : nullptr,
      kchunk, nwg);

  if (ksplit > 1)
    reduce_kernel<<<dim3((M_OUT * N_OUT / 8 + 255) / 256), 256, 0, stream>>>(
        part, out, ksplit);
}